// Round 12
// baseline (9545.065 us; speedup 1.0000x reference)
//
#include <hip/hip_runtime.h>
#include <stdint.h>

#define B_  32
#define T_  1024
#define I_  512
#define H_  1024
#define C_  512
#define G4H 4096

typedef __bf16 bf16x8 __attribute__((ext_vector_type(8)));
typedef float  f32x4  __attribute__((ext_vector_type(4)));
typedef unsigned long long u64;

__device__ __forceinline__ unsigned short f2bf(float f) {
    uint32_t b = __float_as_uint(f);
    b = (b + 0x7FFFu + ((b >> 16) & 1u)) >> 16;
    return (unsigned short)b;
}
__device__ __forceinline__ float bf2f(unsigned short v) {
    return __uint_as_float(((uint32_t)v) << 16);
}
__device__ __forceinline__ float sigf(float x)   { return 1.0f / (1.0f + __expf(-x)); }
__device__ __forceinline__ float tanh_f(float x) { return 2.0f / (1.0f + __expf(-2.0f * x)) - 1.0f; }

// ---------------- fp32 -> bf16 conversion (vectorized x4) ----------------
__global__ void cvt_kernel(const float* __restrict__ src, unsigned short* __restrict__ dst, int n4) {
    int i = blockIdx.x * blockDim.x + threadIdx.x;
    if (i < n4) {
        float4 v = ((const float4*)src)[i];
        ushort4 o;
        o.x = f2bf(v.x); o.y = f2bf(v.y); o.z = f2bf(v.z); o.w = f2bf(v.w);
        ((ushort4*)dst)[i] = o;
    }
}

// row-permuted weight cvt: src row r = gate*1024+unit -> dst row unit*4+gate
template<int K4>
__global__ void cvt_wperm(const float* __restrict__ src, unsigned short* __restrict__ dst) {
    int i = blockIdx.x * blockDim.x + threadIdx.x;   // over 4096*K4
    int r = i / K4, c4 = i % K4;
    float4 v = ((const float4*)src)[i];
    ushort4 o;
    o.x = f2bf(v.x); o.y = f2bf(v.y); o.z = f2bf(v.z); o.w = f2bf(v.w);
    int rp = ((r & 1023) << 2) | (r >> 10);
    ((ushort4*)dst)[rp * K4 + c4] = o;
}

__global__ void bias_kernel(const float* __restrict__ a, const float* __restrict__ b, float* __restrict__ o) {
    int i = blockIdx.x * blockDim.x + threadIdx.x;
    if (i < G4H) o[i] = a[i] + b[i];
}

// ---------------- x_gates GEMM: xg[t][b][permcol] = x[b][t][:] @ Wih_p^T ----------------
__global__ __launch_bounds__(256) void xg_gemm(
        const unsigned short* __restrict__ A,      // [b*1024+t][512] bf16
        const unsigned short* __restrict__ Bw,     // [4096 perm][512] bf16
        unsigned short* __restrict__ out)          // [1024][32][4096] bf16
{
    __shared__ unsigned short As[128 * 64];
    __shared__ unsigned short Bs[128 * 64];
    const int tid  = threadIdx.x;
    const int lane = tid & 63, w = tid >> 6;
    const int wm = w >> 1, wn = w & 1;
    const int mbase = blockIdx.y * 128, nbase = blockIdx.x * 128;
    const int l15 = lane & 15, l4 = lane >> 4;

    f32x4 acc[4][4];
    #pragma unroll
    for (int i = 0; i < 4; i++)
        #pragma unroll
        for (int j = 0; j < 4; j++) acc[i][j] = (f32x4){0.f, 0.f, 0.f, 0.f};

    for (int kb = 0; kb < 8; kb++) {
        __syncthreads();
        #pragma unroll
        for (int i = 0; i < 4; i++) {
            int s = i * 256 + tid;
            int row = s >> 3, g = s & 7;
            int gd = g ^ (row & 7);
            int4 va = *(const int4*)(A  + (size_t)(mbase + row) * 512 + kb * 64 + g * 8);
            *(int4*)(As + row * 64 + gd * 8) = va;
            int4 vb = *(const int4*)(Bw + (size_t)(nbase + row) * 512 + kb * 64 + g * 8);
            *(int4*)(Bs + row * 64 + gd * 8) = vb;
        }
        __syncthreads();
        #pragma unroll
        for (int kk = 0; kk < 2; kk++) {
            bf16x8 af[4], bf[4];
            #pragma unroll
            for (int mt = 0; mt < 4; mt++) {
                int row = wm * 64 + mt * 16 + l15;
                int gg = (kk * 4 + l4) ^ (row & 7);
                af[mt] = *(const bf16x8*)(As + row * 64 + gg * 8);
            }
            #pragma unroll
            for (int nt = 0; nt < 4; nt++) {
                int row = wn * 64 + nt * 16 + l15;
                int gg = (kk * 4 + l4) ^ (row & 7);
                bf[nt] = *(const bf16x8*)(Bs + row * 64 + gg * 8);
            }
            #pragma unroll
            for (int mt = 0; mt < 4; mt++)
                #pragma unroll
                for (int nt = 0; nt < 4; nt++)
                    acc[mt][nt] = __builtin_amdgcn_mfma_f32_16x16x32_bf16(af[mt], bf[nt], acc[mt][nt], 0, 0, 0);
        }
    }
    #pragma unroll
    for (int mt = 0; mt < 4; mt++)
        #pragma unroll
        for (int nt = 0; nt < 4; nt++)
            #pragma unroll
            for (int r = 0; r < 4; r++) {
                int grow = mbase + wm * 64 + mt * 16 + l4 * 4 + r;
                int gcol = nbase + wn * 64 + nt * 16 + l15;
                int b = grow >> 10, t = grow & 1023;
                out[((size_t)t * B_ + b) * G4H + gcol] = f2bf(acc[mt][nt][r]);
            }
}

// ---------------- batch-grouped persistent LSTM (8 independent groups of 32 WGs) ----------------
// 256 WGs x 512 thr (cooperative; 96KB LDS -> 1 WG/CU). Group g = wg>>5 owns
// batches [4g,+4); WG slot = wg&31 owns units [slot*32,+32); wave w owns perm
// cols [slot*128 + w*16, +16) = units [slot*32+w*4,+4) x 4 gates, FULL K=1024:
// W_hh slice in 128 VGPRs (wf[32]); 32 MFMA/wave/step, no cross-wave reduction,
// ZERO __syncthreads in the step loop.
// A operand: 4 valid batch rows (l15&3 clamp -> address broadcast), plain cached
// loads (first-touch, flag-gated). Publish: per-wave 16 h values via LDS pack ->
// 4x8B agent stores -> vmcnt(0) -> LDS monotonic done ctr; 8th wave sets the
// per-WG line-padded agent flag. Wait: wave 0 polls own group's 32 flags
// (lanes<32, 1 line each, sleep), then LDS 'go' broadcast to waves 1-7.
// Groups never interact -> jitter max over 32 WGs, not 128.
__global__ __launch_bounds__(512, 1) void lstm_rec(
        const unsigned short* __restrict__ whh_p,  // [4096 perm][1024] bf16
        const unsigned short* __restrict__ xg,     // [1024][32][4096 perm] bf16
        const float* __restrict__ bias,            // [4096] i,f,g,o blocks
        unsigned short* __restrict__ hall,         // [1025][32][1024] bf16 (slot0 zeroed)
        unsigned int* __restrict__ flags)          // [1024][256][16] dw (zeroed, 64B/flag)
{
    extern __shared__ char smem[];
    float*          exch = (float*)smem;                   // [8][64] f32 = 2048 B
    unsigned short* hx   = (unsigned short*)(smem + 2048); // [8][16] = 256 B
    int*            done = (int*)(smem + 2304);
    int*            go   = (int*)(smem + 2308);

    const int tid  = threadIdx.x;
    const int lane = tid & 63;
    const int w    = tid >> 6;
    const int l15  = lane & 15;
    const int l4   = lane >> 4;
    const int g    = blockIdx.x >> 5;
    const int slot = blockIdx.x & 31;

    // ---- W_hh slice -> VGPRs: wave's 16 perm cols, full K ----
    bf16x8 wf[32];
    {
        const unsigned short* wsrc = whh_p + (size_t)(slot * 128 + w * 16 + l15) * 1024 + l4 * 8;
        #pragma unroll
        for (int ks = 0; ks < 32; ks++)
            wf[ks] = *(const bf16x8*)(wsrc + ks * 32);
    }

    // pointwise lane constants (lanes 0-15: u4 = unit-within-wave, pb = batch)
    const int u4 = (lane >> 2) & 3;
    const int pb = lane & 3;
    const int unit = slot * 32 + w * 4 + u4;
    const float bi = bias[unit], bff = bias[1024 + unit],
                bg = bias[2048 + unit], bo = bias[3072 + unit];
    float cst = 0.0f;

    const unsigned short* xgp = xg + (size_t)(g * 4 + pb) * G4H + (size_t)unit * 4;
    u64 xgr = *(const u64*)xgp;                   // t = 0 gates (4 x bf16)

    if (tid == 0) { *done = 0; *go = -1; }
    __syncthreads();                               // once, before the loop

    const unsigned short* habase = hall + (size_t)(g * 4 + (l15 & 3)) * 1024 + l4 * 8;

    for (int t = 0; t < T_; ++t) {
        // ---- wait for h(t): wave 0 polls 32 group flags; LDS 'go' broadcast ----
        if (t > 0) {
            if (w == 0) {
                if (lane < 32) {
                    const unsigned int* f = flags + ((size_t)(t - 1) * 256 + g * 32 + lane) * 16;
                    while (__hip_atomic_load(f, __ATOMIC_RELAXED, __HIP_MEMORY_SCOPE_AGENT) == 0u)
                        __builtin_amdgcn_s_sleep(2);
                }
                if (lane == 0)
                    __hip_atomic_store(go, t, __ATOMIC_RELAXED, __HIP_MEMORY_SCOPE_WORKGROUP);
            } else {
                while (__hip_atomic_load(go, __ATOMIC_RELAXED, __HIP_MEMORY_SCOPE_WORKGROUP) < t)
                    __builtin_amdgcn_s_sleep(1);
            }
            asm volatile("" ::: "memory");
        }

        // ---- MFMA: full K=1024, 2-acc ILP; A rows = 4 batches (broadcast) ----
        f32x4 a0 = (f32x4){0.f, 0.f, 0.f, 0.f};
        f32x4 a1 = (f32x4){0.f, 0.f, 0.f, 0.f};
        const unsigned short* ha = habase + (size_t)t * (B_ * H_);
        #pragma unroll
        for (int ks = 0; ks < 32; ks += 2) {
            bf16x8 f0 = *(const bf16x8*)(ha + ks * 32);
            bf16x8 f1 = *(const bf16x8*)(ha + ks * 32 + 32);
            a0 = __builtin_amdgcn_mfma_f32_16x16x32_bf16(f0, wf[ks],     a0, 0, 0, 0);
            a1 = __builtin_amdgcn_mfma_f32_16x16x32_bf16(f1, wf[ks + 1], a1, 0, 0, 0);
        }
        a0[0] += a1[0]; a0[1] += a1[1]; a0[2] += a1[2]; a0[3] += a1[3];

        // ---- intra-wave gate exchange + pointwise (lanes 0-15) ----
        u64 xg_cur = xgr;
        {
            int tn = (t + 1 < T_) ? t + 1 : T_ - 1;
            xgr = *(const u64*)(xgp + (size_t)tn * (B_ * G4H));   // prefetch, in flight
        }
        if (lane < 16) {
            // C layout: col = l15 (this wave's perm col), batch = reg r (rows 0-3)
            float* ex = exch + w * 64;
            ex[l15 * 4 + 0] = a0[0];
            ex[l15 * 4 + 1] = a0[1];
            ex[l15 * 4 + 2] = a0[2];
            ex[l15 * 4 + 3] = a0[3];
            // read own (unit u4, batch pb): gates at cols u4*4+gate
            union { u64 q; unsigned short s[4]; } xu; xu.q = xg_cur;
            float qi = bi  + ex[(u4 * 4 + 0) * 4 + pb] + bf2f(xu.s[0]);
            float qf = bff + ex[(u4 * 4 + 1) * 4 + pb] + bf2f(xu.s[1]);
            float qg = bg  + ex[(u4 * 4 + 2) * 4 + pb] + bf2f(xu.s[2]);
            float qo = bo  + ex[(u4 * 4 + 3) * 4 + pb] + bf2f(xu.s[3]);
            float ig = sigf(qi), fg = sigf(qf), gv = tanh_f(qg), og = sigf(qo);
            cst = fg * cst + ig * gv;
            hx[w * 16 + pb * 4 + u4] = f2bf(og * tanh_f(cst));
        }
        if (lane < 4) {
            u64 hq = *(const u64*)(hx + w * 16 + lane * 4);
            u64* dst = (u64*)(hall + ((size_t)(t + 1) * B_ + g * 4 + lane) * 1024
                              + slot * 32 + w * 4);
            __hip_atomic_store(dst, hq, __ATOMIC_RELAXED, __HIP_MEMORY_SCOPE_AGENT);
        }
        asm volatile("s_waitcnt vmcnt(0)" ::: "memory");   // this wave's h at LLC
        if (lane == 0) {
            int old = __hip_atomic_fetch_add(done, 1, __ATOMIC_RELAXED, __HIP_MEMORY_SCOPE_WORKGROUP);
            if (old == t * 8 + 7)      // 8th wave of this WG at step t
                __hip_atomic_store(flags + ((size_t)t * 256 + blockIdx.x) * 16, 1u,
                                   __ATOMIC_RELAXED, __HIP_MEMORY_SCOPE_AGENT);
        }
    }
}

// ---------------- output GEMMs: C[M x N] = A[M x 1024] * B[N x 1024]^T + bias ----------------
template<int PERM>
__global__ __launch_bounds__(256) void gemm_bt(
        const unsigned short* __restrict__ A,
        const unsigned short* __restrict__ Bw,
        const float* __restrict__ bias,
        float* __restrict__ out)
{
    __shared__ unsigned short As[128 * 64];
    __shared__ unsigned short Bs[128 * 64];
    const int tid  = threadIdx.x;
    const int lane = tid & 63, w = tid >> 6;
    const int wm = w >> 1, wn = w & 1;
    const int mbase = blockIdx.y * 128, nbase = blockIdx.x * 128;
    const int l15 = lane & 15, l4 = lane >> 4;

    f32x4 acc[4][4];
    #pragma unroll
    for (int i = 0; i < 4; i++)
        #pragma unroll
        for (int j = 0; j < 4; j++) acc[i][j] = (f32x4){0.f, 0.f, 0.f, 0.f};

    for (int kb = 0; kb < 16; kb++) {
        __syncthreads();
        #pragma unroll
        for (int i = 0; i < 4; i++) {
            int s = i * 256 + tid;
            int row = s >> 3, g = s & 7;
            int gd = g ^ (row & 7);
            int4 va = *(const int4*)(A  + (size_t)(mbase + row) * 1024 + kb * 64 + g * 8);
            *(int4*)(As + row * 64 + gd * 8) = va;
            int4 vb = *(const int4*)(Bw + (size_t)(nbase + row) * 1024 + kb * 64 + g * 8);
            *(int4*)(Bs + row * 64 + gd * 8) = vb;
        }
        __syncthreads();
        #pragma unroll
        for (int kk = 0; kk < 2; kk++) {
            bf16x8 af[4], bf[4];
            #pragma unroll
            for (int mt = 0; mt < 4; mt++) {
                int row = wm * 64 + mt * 16 + l15;
                int gg = (kk * 4 + l4) ^ (row & 7);
                af[mt] = *(const bf16x8*)(As + row * 64 + gg * 8);
            }
            #pragma unroll
            for (int nt = 0; nt < 4; nt++) {
                int row = wn * 64 + nt * 16 + l15;
                int gg = (kk * 4 + l4) ^ (row & 7);
                bf[nt] = *(const bf16x8*)(Bs + row * 64 + gg * 8);
            }
            #pragma unroll
            for (int mt = 0; mt < 4; mt++)
                #pragma unroll
                for (int nt = 0; nt < 4; nt++)
                    acc[mt][nt] = __builtin_amdgcn_mfma_f32_16x16x32_bf16(af[mt], bf[nt], acc[mt][nt], 0, 0, 0);
        }
    }
    #pragma unroll
    for (int mt = 0; mt < 4; mt++)
        #pragma unroll
        for (int nt = 0; nt < 4; nt++)
            #pragma unroll
            for (int r = 0; r < 4; r++) {
                int grow = mbase + wm * 64 + mt * 16 + l4 * 4 + r;
                int gcol = nbase + wn * 64 + nt * 16 + l15;
                float v = acc[mt][nt][r] + bias[gcol];
                int idx;
                if (PERM == 1) {
                    int tt = grow >> 5, bb = grow & 31;
                    idx = (bb * 1024 + tt) * 512 + gcol;
                } else {
                    idx = grow * 1024 + gcol;
                }
                out[idx] = v;
            }
}

// ---------------- host ----------------
extern "C" void kernel_launch(void* const* d_in, const int* in_sizes, int n_in,
                              void* d_out, int out_size, void* d_ws, size_t ws_size,
                              hipStream_t stream) {
    (void)in_sizes; (void)n_in; (void)out_size; (void)ws_size;
    const float* x    = (const float*)d_in[0];
    const float* Wih  = (const float*)d_in[1];
    const float* Whh  = (const float*)d_in[2];
    const float* bih  = (const float*)d_in[3];
    const float* bhh  = (const float*)d_in[4];
    const float* fcw  = (const float*)d_in[5];
    const float* fcb  = (const float*)d_in[6];
    const float* lnw  = (const float*)d_in[7];
    const float* lnb  = (const float*)d_in[8];
    float* out = (float*)d_out;

    char* ws = (char*)d_ws;
    size_t o = 0;
    unsigned short* whh_p = (unsigned short*)(ws + o); o += 8388608;   // [4096p][1024]
    unsigned short* wih_p = (unsigned short*)(ws + o); o += 4194304;   // [4096p][512]
    unsigned short* fcw_b = (unsigned short*)(ws + o); o += 1048576;
    unsigned short* lnw_b = (unsigned short*)(ws + o); o += 2097152;
    float*          bias_c = (float*)(ws + o);         o += 16384;
    unsigned short* x_b   = (unsigned short*)(ws + o); o += 33554432;  // [B][T][I] bf16
    unsigned short* hall  = (unsigned short*)(ws + o); o += 67174400;  // [1025][32][1024]
    unsigned short* xgbuf = (unsigned short*)(ws + o); o += 268435456; // [1024][32][4096]
    unsigned int*   flags = (unsigned int*)(ws + o);   o += 16777216;  // [1024][256][16] dw

    hipMemsetAsync(flags, 0, 16777216, stream);
    hipMemsetAsync(hall, 0, 65536, stream);            // h slot 0 = zeros

    cvt_wperm<256><<<4096, 256, 0, stream>>>(Whh, whh_p);
    cvt_wperm<128><<<2048, 256, 0, stream>>>(Wih, wih_p);
    cvt_kernel<<<512,  256, 0, stream>>>(fcw, fcw_b, 524288 / 4);
    cvt_kernel<<<1024, 256, 0, stream>>>(lnw, lnw_b, 1048576 / 4);
    cvt_kernel<<<16384, 256, 0, stream>>>(x, x_b, 16777216 / 4);       // [B][T][I] bf16
    bias_kernel<<<16, 256, 0, stream>>>(bih, bhh, bias_c);
    xg_gemm<<<dim3(32, 256), 256, 0, stream>>>(x_b, wih_p, xgbuf);

    const unsigned short* a0 = whh_p;
    const unsigned short* a1 = xgbuf;
    const float*          a2 = bias_c;
    unsigned short*       a3 = hall;
    unsigned int*         a4 = flags;
    void* args[5] = { (void*)&a0, (void*)&a1, (void*)&a2, (void*)&a3, (void*)&a4 };
    hipLaunchCooperativeKernel((void*)lstm_rec, dim3(256), dim3(512), args,
                               (unsigned)98304, stream);

    const unsigned short* hseq = hall + 32768;  // slot 1 = h at t=0
    gemm_bt<1><<<dim3(4, 256), 256, 0, stream>>>(hseq, fcw_b, fcb, out);
    gemm_bt<2><<<dim3(8, 256), 256, 0, stream>>>(hseq, lnw_b, lnb, out + 16777216);
}

// Round 13
// 4452.611 us; speedup vs baseline: 2.1437x; 2.1437x over previous
//
#include <hip/hip_runtime.h>
#include <stdint.h>

#define B_  32
#define T_  1024
#define I_  512
#define H_  1024
#define C_  512
#define G4H 4096
#define NWG 128

typedef __bf16 bf16x8 __attribute__((ext_vector_type(8)));
typedef float  f32x4  __attribute__((ext_vector_type(4)));
typedef unsigned long long u64;

__device__ __forceinline__ unsigned short f2bf(float f) {
    uint32_t b = __float_as_uint(f);
    b = (b + 0x7FFFu + ((b >> 16) & 1u)) >> 16;
    return (unsigned short)b;
}
__device__ __forceinline__ float sigf(float x)   { return 1.0f / (1.0f + __expf(-x)); }
__device__ __forceinline__ float tanh_f(float x) { return 2.0f / (1.0f + __expf(-2.0f * x)) - 1.0f; }

// ---------------- fp32 -> bf16 conversion (vectorized x4) ----------------
__global__ void cvt_kernel(const float* __restrict__ src, unsigned short* __restrict__ dst, int n4) {
    int i = blockIdx.x * blockDim.x + threadIdx.x;
    if (i < n4) {
        float4 v = ((const float4*)src)[i];
        ushort4 o;
        o.x = f2bf(v.x); o.y = f2bf(v.y); o.z = f2bf(v.z); o.w = f2bf(v.w);
        ((ushort4*)dst)[i] = o;
    }
}

// x: [B][T][I] fp32 -> [T][B][I] bf16 (per-step slice contiguous 32KB)
__global__ void cvt_x_kernel(const float* __restrict__ src, unsigned short* __restrict__ dst) {
    int i4 = blockIdx.x * blockDim.x + threadIdx.x;       // over B*T*I/4
    int b   = i4 / (T_ * I_ / 4);
    int rem = i4 % (T_ * I_ / 4);
    int t   = rem / (I_ / 4);
    int c4  = rem % (I_ / 4);
    float4 v = ((const float4*)src)[i4];
    ushort4 o;
    o.x = f2bf(v.x); o.y = f2bf(v.y); o.z = f2bf(v.z); o.w = f2bf(v.w);
    ((ushort4*)dst)[(t * B_ + b) * (I_ / 4) + c4] = o;
}

__global__ void bias_kernel(const float* __restrict__ a, const float* __restrict__ b, float* __restrict__ o) {
    int i = blockIdx.x * blockDim.x + threadIdx.x;
    if (i < G4H) o[i] = a[i] + b[i];
}

// ---------------- persistent LSTM recurrence (R2 skeleton, line-padded flags) ----------------
// 128 WGs x 512 threads (cooperative for co-residency; NO grid.sync).
// WG wg owns hidden units [wg*8, wg*8+8) -> 32 gate cols.
// LDS W slice [32 cols][1536 K] bf16, XOR-swizzled by 16B granule (g ^ (col&7)).
// K split per wave wq: h-K [wq*128,+128) (4 mfma k-steps), x-K [wq*64,+64) (2).
// Cross-WG h exchange: bulk publish (tid<64, 8B agent stores) -> barrier ->
// single flag store by tid==0. EACH FLAG OWNS A FULL 64B LINE (stride 16 dw):
// producers never false-share; each flag line is polled by exactly one lane
// per WG (128 pollers/line with s_sleep(1)) -> no line congestion.
__global__ __launch_bounds__(512, 1) void lstm_rec(
        const unsigned short* __restrict__ whh,   // [4096][1024] bf16
        const unsigned short* __restrict__ wih,   // [4096][512]  bf16
        const unsigned short* __restrict__ xb,    // [1024][32][512] bf16
        const float* __restrict__ bias,           // [4096] (b_ih + b_hh)
        unsigned short* __restrict__ hall,        // [1025][32][1024] bf16 (slot 0 pre-zeroed)
        unsigned int* __restrict__ flags)         // [1024][128][16] dw (pre-zeroed, 64B/flag)
{
    extern __shared__ char smem[];
    unsigned short* Wlds    = (unsigned short*)smem;                     // 98304 B
    float*          scratch = (float*)(smem + 98304);                    // 32768 B
    unsigned short* hstage  = (unsigned short*)(smem + 98304 + 32768);   // 512 B

    const int tid  = threadIdx.x;
    const int wg   = blockIdx.x;
    const int lane = tid & 63;
    const int wq   = tid >> 6;          // wave id 0..7
    const int l15  = lane & 15;
    const int l4   = lane >> 4;

    // ---- one-time: stage W slice into LDS (swizzled) ----
    for (int s = tid; s < 32 * 192; s += 512) {
        int col = s / 192, g = s % 192;
        int grow = (col >> 3) * H_ + wg * 8 + (col & 7);   // global gate row
        const unsigned short* src = (g < 128) ? (whh + grow * H_ + g * 8)
                                              : (wih + grow * I_ + (g - 128) * 8);
        int4 v = *(const int4*)src;
        int gd = g ^ (col & 7);
        *(int4*)(Wlds + col * 1536 + gd * 8) = v;
    }
    float bs0 = 0.f, bs1 = 0.f, bs2 = 0.f, bs3 = 0.f;
    if (tid < 256) {
        int u = tid & 7;
        bs0 = bias[0 * H_ + wg * 8 + u];
        bs1 = bias[1 * H_ + wg * 8 + u];
        bs2 = bias[2 * H_ + wg * 8 + u];
        bs3 = bias[3 * H_ + wg * 8 + u];
    }
    __syncthreads();

    float c_state = 0.0f;

    for (int t = 0; t < T_; ++t) {
        f32x4 acc[2][2];
        #pragma unroll
        for (int a = 0; a < 2; a++)
            #pragma unroll
            for (int b = 0; b < 2; b++) acc[a][b] = (f32x4){0.f, 0.f, 0.f, 0.f};

        // ---- x-part first: no dependency on h_t, hides producer latency ----
        #pragma unroll
        for (int kxs = 0; kxs < 2; kxs++) {
            int kk = wq * 64 + kxs * 32 + l4 * 8;      // x-K local [0,512)
            bf16x8 af[2];
            #pragma unroll
            for (int mt = 0; mt < 2; mt++) {
                int bb = mt * 16 + l15;
                af[mt] = *(const bf16x8*)(xb + ((size_t)t * B_ + bb) * I_ + kk);
            }
            int gbase = 128 + (kk >> 3);               // x granules at 128..191
            bf16x8 bfr[2];
            #pragma unroll
            for (int nt = 0; nt < 2; nt++) {
                int col = nt * 16 + l15;
                int gg = gbase ^ (col & 7);
                bfr[nt] = *(const bf16x8*)(Wlds + col * 1536 + gg * 8);
            }
            #pragma unroll
            for (int mt = 0; mt < 2; mt++)
                #pragma unroll
                for (int nt = 0; nt < 2; nt++)
                    acc[mt][nt] = __builtin_amdgcn_mfma_f32_16x16x32_bf16(af[mt], bfr[nt], acc[mt][nt], 0, 0, 0);
        }

        // ---- wait for all h_t slices: one lane per flag LINE ----
        if (t > 0) {
            if (tid < NWG) {
                const unsigned int* f = flags + ((size_t)(t - 1) * NWG + tid) * 16;
                while (__hip_atomic_load(f, __ATOMIC_RELAXED, __HIP_MEMORY_SCOPE_AGENT) == 0u)
                    __builtin_amdgcn_s_sleep(1);
            }
            __syncthreads();
            asm volatile("" ::: "memory");
        }

        // ---- h-part ----
        const unsigned short* hprev = hall + (size_t)t * (B_ * H_);
        #pragma unroll
        for (int khs = 0; khs < 4; khs++) {
            int kk = wq * 128 + khs * 32 + l4 * 8;     // h-K [0,1024)
            bf16x8 af[2];
            #pragma unroll
            for (int mt = 0; mt < 2; mt++) {
                int bb = mt * 16 + l15;
                af[mt] = *(const bf16x8*)(hprev + bb * H_ + kk);
            }
            int gbase = kk >> 3;
            bf16x8 bfr[2];
            #pragma unroll
            for (int nt = 0; nt < 2; nt++) {
                int col = nt * 16 + l15;
                int gg = gbase ^ (col & 7);
                bfr[nt] = *(const bf16x8*)(Wlds + col * 1536 + gg * 8);
            }
            #pragma unroll
            for (int mt = 0; mt < 2; mt++)
                #pragma unroll
                for (int nt = 0; nt < 2; nt++)
                    acc[mt][nt] = __builtin_amdgcn_mfma_f32_16x16x32_bf16(af[mt], bfr[nt], acc[mt][nt], 0, 0, 0);
        }

        // ---- partial results -> LDS scratch (bank-swizzled writes, <=2-way) ----
        float* myscr = scratch + wq * 1024;
        #pragma unroll
        for (int mt = 0; mt < 2; mt++)
            #pragma unroll
            for (int nt = 0; nt < 2; nt++)
                #pragma unroll
                for (int r = 0; r < 4; r++) {
                    int bb  = mt * 16 + l4 * 4 + r;       // batch (D row)
                    int col = nt * 16 + l15;              // gate col (D col)
                    myscr[bb * 32 + (col ^ ((bb & 7) << 2))] = acc[mt][nt][r];
                }
        __syncthreads();

        // ---- pointwise LSTM cell: 256 threads = 32 batches x 8 units ----
        if (tid < 256) {
            int bb = tid >> 3, u = tid & 7;
            int sw = (bb & 7) << 2;
            float p0 = bs0, p1 = bs1, p2 = bs2, p3 = bs3;
            const float* base = scratch + bb * 32;
            #pragma unroll
            for (int q = 0; q < 8; q++) {
                const float* sc = base + q * 1024;
                p0 += sc[(u)      ^ sw];
                p1 += sc[(8 + u)  ^ sw];
                p2 += sc[(16 + u) ^ sw];
                p3 += sc[(24 + u) ^ sw];
            }
            float ig = sigf(p0), fg = sigf(p1), gg = tanh_f(p2), og = sigf(p3);
            c_state = fg * c_state + ig * gg;
            float h = og * tanh_f(c_state);
            hstage[bb * 8 + u] = f2bf(h);
        }
        __syncthreads();

        // ---- publish h slice: L2-bypass 8B stores -> LLC-coherent ----
        if (tid < 64) {
            int bb = tid >> 1, part = tid & 1;
            u64 q = *(u64*)(hstage + bb * 8 + part * 4);
            u64* dst = (u64*)(hall + ((size_t)(t + 1) * B_ + bb) * H_ + wg * 8 + part * 4);
            __hip_atomic_store(dst, q, __ATOMIC_RELAXED, __HIP_MEMORY_SCOPE_AGENT);
        }
        __syncthreads();   // drains vmcnt per thread -> all h stores at LLC
        if (tid == 0)
            __hip_atomic_store(flags + ((size_t)t * NWG + wg) * 16, 1u,
                               __ATOMIC_RELAXED, __HIP_MEMORY_SCOPE_AGENT);
    }
}

// ---------------- output GEMMs: C[M x N] = A[M x 1024] * B[N x 1024]^T + bias ----------------
template<int PERM>
__global__ __launch_bounds__(256) void gemm_bt(
        const unsigned short* __restrict__ A,
        const unsigned short* __restrict__ Bw,
        const float* __restrict__ bias,
        float* __restrict__ out)
{
    __shared__ unsigned short As[128 * 64];
    __shared__ unsigned short Bs[128 * 64];
    const int tid  = threadIdx.x;
    const int lane = tid & 63, w = tid >> 6;
    const int wm = w >> 1, wn = w & 1;
    const int mbase = blockIdx.y * 128, nbase = blockIdx.x * 128;
    const int l15 = lane & 15, l4 = lane >> 4;

    f32x4 acc[4][4];
    #pragma unroll
    for (int i = 0; i < 4; i++)
        #pragma unroll
        for (int j = 0; j < 4; j++) acc[i][j] = (f32x4){0.f, 0.f, 0.f, 0.f};

    for (int kb = 0; kb < 16; kb++) {
        __syncthreads();
        #pragma unroll
        for (int i = 0; i < 4; i++) {
            int s = i * 256 + tid;
            int row = s >> 3, g = s & 7;
            int gd = g ^ (row & 7);
            int4 va = *(const int4*)(A  + (size_t)(mbase + row) * 1024 + kb * 64 + g * 8);
            *(int4*)(As + row * 64 + gd * 8) = va;
            int4 vb = *(const int4*)(Bw + (size_t)(nbase + row) * 1024 + kb * 64 + g * 8);
            *(int4*)(Bs + row * 64 + gd * 8) = vb;
        }
        __syncthreads();
        #pragma unroll
        for (int kk = 0; kk < 2; kk++) {
            bf16x8 af[4], bf[4];
            #pragma unroll
            for (int mt = 0; mt < 4; mt++) {
                int row = wm * 64 + mt * 16 + l15;
                int gg = (kk * 4 + l4) ^ (row & 7);
                af[mt] = *(const bf16x8*)(As + row * 64 + gg * 8);
            }
            #pragma unroll
            for (int nt = 0; nt < 4; nt++) {
                int row = wn * 64 + nt * 16 + l15;
                int gg = (kk * 4 + l4) ^ (row & 7);
                bf[nt] = *(const bf16x8*)(Bs + row * 64 + gg * 8);
            }
            #pragma unroll
            for (int mt = 0; mt < 4; mt++)
                #pragma unroll
                for (int nt = 0; nt < 4; nt++)
                    acc[mt][nt] = __builtin_amdgcn_mfma_f32_16x16x32_bf16(af[mt], bf[nt], acc[mt][nt], 0, 0, 0);
        }
    }
    #pragma unroll
    for (int mt = 0; mt < 4; mt++)
        #pragma unroll
        for (int nt = 0; nt < 4; nt++)
            #pragma unroll
            for (int r = 0; r < 4; r++) {
                int grow = mbase + wm * 64 + mt * 16 + l4 * 4 + r;
                int gcol = nbase + wn * 64 + nt * 16 + l15;
                float v = acc[mt][nt][r] + bias[gcol];
                int idx;
                if (PERM == 1) {
                    int tt = grow >> 5, bb = grow & 31;
                    idx = (bb * 1024 + tt) * 512 + gcol;
                } else {
                    idx = grow * 1024 + gcol;
                }
                out[idx] = v;
            }
}

// ---------------- host ----------------
extern "C" void kernel_launch(void* const* d_in, const int* in_sizes, int n_in,
                              void* d_out, int out_size, void* d_ws, size_t ws_size,
                              hipStream_t stream) {
    (void)in_sizes; (void)n_in; (void)out_size; (void)ws_size;
    const float* x    = (const float*)d_in[0];
    const float* Wih  = (const float*)d_in[1];
    const float* Whh  = (const float*)d_in[2];
    const float* bih  = (const float*)d_in[3];
    const float* bhh  = (const float*)d_in[4];
    const float* fcw  = (const float*)d_in[5];
    const float* fcb  = (const float*)d_in[6];
    const float* lnw  = (const float*)d_in[7];
    const float* lnb  = (const float*)d_in[8];
    float* out = (float*)d_out;

    char* ws = (char*)d_ws;
    size_t o = 0;
    unsigned short* whh_b = (unsigned short*)(ws + o); o += 8388608;   // [4096][1024]
    unsigned short* wih_b = (unsigned short*)(ws + o); o += 4194304;   // [4096][512]
    unsigned short* fcw_b = (unsigned short*)(ws + o); o += 1048576;   // [512][1024]
    unsigned short* lnw_b = (unsigned short*)(ws + o); o += 2097152;   // [1024][1024]
    unsigned short* x_b   = (unsigned short*)(ws + o); o += 33554432;  // [1024][32][512]
    float*          bias_c = (float*)(ws + o);         o += 16384;     // [4096]
    unsigned short* hall  = (unsigned short*)(ws + o); o += 67174400;  // [1025][32][1024]
    unsigned int*   flags = (unsigned int*)(ws + o);   o += 8388608;   // [1024][128][16] dw

    hipMemsetAsync(flags, 0, 8388608, stream);
    hipMemsetAsync(hall, 0, 65536, stream);      // h slot 0 = zeros

    cvt_kernel<<<4096,  256, 0, stream>>>(Whh, whh_b, 4194304 / 4);
    cvt_kernel<<<2048,  256, 0, stream>>>(Wih, wih_b, 2097152 / 4);
    cvt_kernel<<<512,   256, 0, stream>>>(fcw, fcw_b, 524288 / 4);
    cvt_kernel<<<1024,  256, 0, stream>>>(lnw, lnw_b, 1048576 / 4);
    cvt_x_kernel<<<16384, 256, 0, stream>>>(x, x_b);
    bias_kernel<<<16, 256, 0, stream>>>(bih, bhh, bias_c);

    const unsigned short* a0 = whh_b;
    const unsigned short* a1 = wih_b;
    const unsigned short* a2 = x_b;
    const float*          a3 = bias_c;
    unsigned short*       a4 = hall;
    unsigned int*         a5 = flags;
    void* args[6] = { (void*)&a0, (void*)&a1, (void*)&a2, (void*)&a3, (void*)&a4, (void*)&a5 };
    hipLaunchCooperativeKernel((void*)lstm_rec, dim3(NWG), dim3(512), args,
                               (unsigned)(98304 + 32768 + 512), stream);

    const unsigned short* hseq = hall + 32768;  // slot 1 = h at t=0
    gemm_bt<1><<<dim3(4, 256), 256, 0, stream>>>(hseq, fcw_b, fcb, out);
    gemm_bt<2><<<dim3(8, 256), 256, 0, stream>>>(hseq, lnw_b, lnb, out + 16777216);
}